// Round 2
// baseline (168.502 us; speedup 1.0000x reference)
//
#include <hip/hip_runtime.h>
#include <math.h>

// Problem geometry (fixed by setup_inputs)
#define NN 2
#define DD 160
#define HH 192
#define WW 160
#define DO 154   // DD-6
#define HO 186   // HH-6
#define WO 154   // WW-6

#define NWO 3    // wo tiles of 64
#define HOT 8    // ho tile
#define NHO 24   // ceil(186/8)
#define ZCH 7    // z chunks: 154 = 7*22 exactly -> every block nslice=28=4*7
#define ZOC 22
#define NB (NWO * NHO * NN * ZCH)   // 3*24*14 = 1008 blocks  (~3.94/CU, 4 resident)

// LDS-only barrier: s_waitcnt lgkmcnt(0) (vmcnt left outstanding) + s_barrier.
// Global prefetch loads stay in flight across the barrier (CK block_sync_lds).
#define LDS_SYNC() do { __builtin_amdgcn_s_waitcnt(0xC07F); __builtin_amdgcn_s_barrier(); } while (0)

__device__ __forceinline__ float block_sum(float v, float* sm) {
  int tid = threadIdx.x;
  sm[tid] = v;
  __syncthreads();
#pragma unroll
  for (int off = 128; off > 0; off >>= 1) {
    if (tid < off) sm[tid] += sm[tid + off];
    __syncthreads();
  }
  float r = sm[0];
  __syncthreads();
  return r;
}

__device__ __forceinline__ float block_min(float v, float* sm) {
  int tid = threadIdx.x;
  sm[tid] = v;
  __syncthreads();
#pragma unroll
  for (int off = 128; off > 0; off >>= 1) {
    if (tid < off) sm[tid] = fminf(sm[tid], sm[tid + off]);
    __syncthreads();
  }
  float r = sm[0];
  __syncthreads();
  return r;
}

__device__ __forceinline__ float wave_sum(float v) {
  v += __shfl_xor(v, 32); v += __shfl_xor(v, 16); v += __shfl_xor(v, 8);
  v += __shfl_xor(v, 4);  v += __shfl_xor(v, 2);  v += __shfl_xor(v, 1);
  return v;
}

__device__ __forceinline__ float wave_min(float v) {
  v = fminf(v, __shfl_xor(v, 32)); v = fminf(v, __shfl_xor(v, 16));
  v = fminf(v, __shfl_xor(v, 8));  v = fminf(v, __shfl_xor(v, 4));
  v = fminf(v, __shfl_xor(v, 2));  v = fminf(v, __shfl_xor(v, 1));
  return v;
}

// 7-tap sliding W-sum over 10 inputs -> 4 outputs (one float4 store, dense layout).
#define SLIDE7(V, M) do { \
  float s0 = ((V[0]+V[1])+(V[2]+V[3])) + ((V[4]+V[5])+V[6]); \
  float s1 = s0 - V[0] + V[7]; \
  float s2 = s1 - V[1] + V[8]; \
  float s3 = s2 - V[2] + V[9]; \
  *(float4*)&R[M][rA][c4] = make_float4(s0, s1, s2, s3); \
} while (0)

__global__ __launch_bounds__(256, 4) void ncc_fused(const float* __restrict__ X,
                                                    const float* __restrict__ Y,
                                                    float* __restrict__ part) {
  __shared__ __align__(16) float R[5][14][64];   // 17.9 KB W-filtered moment rows
  __shared__ __align__(16) float Mh[5][HOT][64]; // 10.2 KB W+H-filtered moments
  __shared__ float red[4][5];

  const int tid = threadIdx.x;
  const int tx = tid & 63, ty = tid >> 6;
  const int wo0 = blockIdx.x * 64;
  const int ho0 = blockIdx.y * HOT;
  const int n   = blockIdx.z / ZCH;
  const int ck  = blockIdx.z % ZCH;
  const int z0  = ck * ZOC;
  const int zout = min(ZOC, DO - z0);   // == 22 always (154 = 7*22)
  const int nslice = zout + 6;          // == 28

  const int wo = wo0 + tx;
  const bool act0 = (wo < WO) && (ho0 + ty < HO);
  const bool act1 = (wo < WO) && (ho0 + ty + 4 < HO);

  const size_t slice = (size_t)HH * WW;
  const float* Xn = X + (size_t)n * DD * slice;
  const float* Yn = Y + (size_t)n * DD * slice;
  const float inv_nw = 1.0f / 343.0f;
  const float LO = -1.0f - 1e-5f, HI = 1.0f + 1e-5f;

  // Phase-A item: 224 items; item p -> row rA=p>>4 (0..13), 4 outputs at cols c4..c4+3.
  // All 4 waves issue global loads + SLIDE7 work (balance; round-1's W8 packed it on 1.75 waves).
  const int pA  = tid;
  const bool hasA = (pA < 224);
  const int rA  = pA >> 4;
  const int c4  = (pA & 15) << 2;
  const int hA  = ho0 + rA;
  const int baseW = wo0 + c4;                  // multiple of 4
  const bool okA  = hasA && (hA < HH) && (baseW < WO);
  const bool tail = okA && (baseW + 10 > WW);  // only baseW==152: read 8, zero 2
  const float* XrowA = Xn + (size_t)hA * WW + baseW;
  const float* YrowA = Yn + (size_t)hA * WW + baseW;

  float4 lx0={0,0,0,0}, lx1={0,0,0,0};
  float4 ly0={0,0,0,0}, ly1={0,0,0,0};
  float2 lx2={0,0}, ly2={0,0};

  auto loadA = [&](int s_in) {
    if (okA) {
      const float* xp = XrowA + (size_t)(z0 + s_in) * slice;
      const float* yp = YrowA + (size_t)(z0 + s_in) * slice;
      lx0 = *(const float4*)xp;       lx1 = *(const float4*)(xp + 4);
      ly0 = *(const float4*)yp;       ly1 = *(const float4*)(yp + 4);
      if (!tail) { lx2 = *(const float2*)(xp + 8); ly2 = *(const float2*)(yp + 8); }
      else       { lx2 = make_float2(0.f, 0.f);    ly2 = make_float2(0.f, 0.f); }
    }
  };

  auto storeA = [&]() {
    if (okA) {
      const float x[10] = {lx0.x,lx0.y,lx0.z,lx0.w, lx1.x,lx1.y,lx1.z,lx1.w, lx2.x,lx2.y};
      const float y[10] = {ly0.x,ly0.y,ly0.z,ly0.w, ly1.x,ly1.y,ly1.z,ly1.w, ly2.x,ly2.y};
      SLIDE7(x, 0);
      SLIDE7(y, 1);
      {
        float t[10];
#pragma unroll
        for (int i = 0; i < 10; ++i) t[i] = x[i] * x[i];
        SLIDE7(t, 2);
      }
      {
        float t[10];
#pragma unroll
        for (int i = 0; i < 10; ++i) t[i] = y[i] * y[i];
        SLIDE7(t, 3);
      }
      {
        float t[10];
#pragma unroll
        for (int i = 0; i < 10; ++i) t[i] = x[i] * y[i];
        SLIDE7(t, 4);
      }
    }
  };

  // Phase H: 7-tap sliding H-sums, 14 rows -> 8 outputs per (ch, w). 320 items.
  auto phaseHitem = [&](int ch, int w) {
    const float* rp = &R[ch][0][w];
    float r0=rp[0],   r1=rp[64],  r2=rp[128], r3=rp[192], r4=rp[256],
          r5=rp[320], r6=rp[384], r7=rp[448], r8=rp[512], r9=rp[576],
          r10=rp[640], r11=rp[704], r12=rp[768], r13=rp[832];
    float m0 = ((r0+r1)+(r2+r3)) + ((r4+r5)+r6);
    float m1 = m0 - r0 + r7;
    float m2 = m1 - r1 + r8;
    float m3 = m2 - r2 + r9;
    float m4 = m3 - r3 + r10;
    float m5 = m4 - r4 + r11;
    float m6 = m5 - r5 + r12;
    float m7 = m6 - r6 + r13;
    Mh[ch][0][w]=m0; Mh[ch][1][w]=m1; Mh[ch][2][w]=m2; Mh[ch][3][w]=m3;
    Mh[ch][4][w]=m4; Mh[ch][5][w]=m5; Mh[ch][6][w]=m6; Mh[ch][7][w]=m7;
  };
  auto phaseH = [&]() {
    phaseHitem(ty, tx);
    if (ty == 3) phaseHitem(4, tx);   // wave 3's phase-A is half-masked -> give it ch4
  };

  // Sliding-window Z accumulation: zs += m_new - hist[u]; hist[u] = m_new.
  // Ring index u is static (loop unrolled by 7) -> all registers.
  float zs0[2]={0,0}, zs1[2]={0,0}, zs2[2]={0,0}, zs3[2]={0,0}, zs4[2]={0,0};
  float h0[2][7], h1[2][7], h2[2][7], h3[2][7], h4[2][7];
#pragma unroll
  for (int j = 0; j < 7; ++j) {
    h0[0][j]=0.f; h1[0][j]=0.f; h2[0][j]=0.f; h3[0][j]=0.f; h4[0][j]=0.f;
    h0[1][j]=0.f; h1[1][j]=0.f; h2[1][j]=0.f; h3[1][j]=0.f; h4[1][j]=0.f;
  }
  float p_snv = 0.f, p_sn = 0.f, p_sv = 0.f, p_cnt = 0.f, p_vmin = 3.4e38f;

  loadA(0);
  storeA();
  __syncthreads();

  for (int sb = 0; sb < nslice; sb += 7) {
#pragma unroll
    for (int u = 0; u < 7; ++u) {
      const int s = sb + u;
      if (s < nslice) {                       // wave-uniform (always true: 28=4*7)
        if (s + 1 < nslice) loadA(s + 1);     // global -> regs (stays in flight)
        phaseH();                             // R -> Mh
        LDS_SYNC();
        {                                     // Phase O: Mh -> sliding-Z + epilogue
#pragma unroll
          for (int rb = 0; rb < 2; ++rb) {
            const int row = ty + (rb << 2);
            float m0 = Mh[0][row][tx], m1 = Mh[1][row][tx], m2 = Mh[2][row][tx],
                  m3 = Mh[3][row][tx], m4 = Mh[4][row][tx];
            zs0[rb] += m0 - h0[rb][u]; h0[rb][u] = m0;
            zs1[rb] += m1 - h1[rb][u]; h1[rb][u] = m1;
            zs2[rb] += m2 - h2[rb][u]; h2[rb][u] = m2;
            zs3[rb] += m3 - h3[rb][u]; h3[rb][u] = m3;
            zs4[rb] += m4 - h4[rb][u]; h4[rb][u] = m4;
            if (s >= 6 && (rb ? act1 : act0)) {
              float num = zs4[rb] - zs0[rb] * zs1[rb] * inv_nw;
              float d0  = zs2[rb] - zs0[rb] * zs0[rb] * inv_nw;
              float d1  = zs3[rb] - zs1[rb] * zs1[rb] * inv_nw;
              float den = d0 * d1;
              if (den > 1e-5f) {
                float ncc = num * __frsqrt_rn(den);
                if (ncc >= LO && ncc <= HI) {
                  float v = 0.5f * (d0 + d1);
                  p_snv += ncc * v; p_sn += ncc; p_sv += v; p_cnt += 1.f;
                  p_vmin = fminf(p_vmin, v);
                }
              }
            }
          }
        }
        if (s + 1 < nslice) storeA();         // vmcnt wait lands HERE
        LDS_SYNC();
      }
    }
  }

  // Wave-level reduction (6 shfl each), then 4 partials through LDS.
  float r0 = wave_sum(p_snv);
  float r1 = wave_sum(p_sn);
  float r2 = wave_sum(p_sv);
  float r3 = wave_sum(p_cnt);
  float r4 = wave_min(p_vmin);
  if (tx == 0) {
    red[ty][0]=r0; red[ty][1]=r1; red[ty][2]=r2; red[ty][3]=r3; red[ty][4]=r4;
  }
  __syncthreads();
  if (tid == 0) {
    float s0 = (red[0][0]+red[1][0]) + (red[2][0]+red[3][0]);
    float s1 = (red[0][1]+red[1][1]) + (red[2][1]+red[3][1]);
    float s2 = (red[0][2]+red[1][2]) + (red[2][2]+red[3][2]);
    float s3 = (red[0][3]+red[1][3]) + (red[2][3]+red[3][3]);
    float s4 = fminf(fminf(red[0][4],red[1][4]), fminf(red[2][4],red[3][4]));
    const int bid = blockIdx.x + NWO * (blockIdx.y + NHO * blockIdx.z);
    float* pp = part + (size_t)bid * 8;
    pp[0] = s0; pp[1] = s1; pp[2] = s2; pp[3] = s3; pp[4] = s4;
  }
}

// Reduce NB per-block partials; loss = 1 - (S_nv - vmin*S_n)/(S_v - vmin*cnt)
// (the min-max weight scale HIGH/(vmax-vmin+1e-12) cancels in w/sum(w)).
__global__ __launch_bounds__(256) void fin(const float* __restrict__ part,
                                           float* __restrict__ out) {
  __shared__ float sm[256];
  const int tid = threadIdx.x;
  float s0 = 0.f, s1 = 0.f, s2 = 0.f, s3 = 0.f, vm = 3.4e38f;
  for (int b = tid; b < NB; b += 256) {
    const float* pp = part + (size_t)b * 8;
    s0 += pp[0]; s1 += pp[1]; s2 += pp[2]; s3 += pp[3];
    vm = fminf(vm, pp[4]);
  }
  s0 = block_sum(s0, sm);
  s1 = block_sum(s1, sm);
  s2 = block_sum(s2, sm);
  s3 = block_sum(s3, sm);
  vm = block_min(vm, sm);
  if (tid == 0) {
    out[0] = 1.0f - (s0 - vm * s1) / (s2 - vm * s3);
  }
}

extern "C" void kernel_launch(void* const* d_in, const int* in_sizes, int n_in,
                              void* d_out, int out_size, void* d_ws, size_t ws_size,
                              hipStream_t stream) {
  const float* X = (const float*)d_in[0];  // y_pred
  const float* Y = (const float*)d_in[1];  // y_true
  // d_in[2]: ones kernel, constant, unused.

  float* part = (float*)d_ws;  // NB * 8 floats = 31.5 KB

  dim3 g(NWO, NHO, NN * ZCH);
  ncc_fused<<<g, 256, 0, stream>>>(X, Y, part);
  fin<<<1, 256, 0, stream>>>(part, (float*)d_out);
}

// Round 3
// 159.758 us; speedup vs baseline: 1.0547x; 1.0547x over previous
//
#include <hip/hip_runtime.h>
#include <math.h>

// Problem geometry (fixed by setup_inputs)
#define NN 2
#define DD 160
#define HH 192
#define WW 160
#define DO 154   // DD-6
#define HO 186   // HH-6
#define WO 154   // WW-6

#define NWO 3    // wo tiles of 64
#define HOT 8    // ho tile
#define NHO 24   // ceil(186/8)
#define ZCH 7    // z chunks: 154 = 7*22 exactly -> every block nslice=28=4*7
#define ZOC 22
#define NSL 28   // ZOC+6, compile-time constant for ALL blocks
#define NB (NWO * NHO * NN * ZCH)   // 3*24*14 = 1008 blocks  (~3.94/CU, 4 resident)

// LDS-only barrier: s_waitcnt lgkmcnt(0) (vmcnt left outstanding) + s_barrier.
// Global prefetch loads stay in flight across the barrier (CK block_sync_lds).
#define LDS_SYNC() do { __builtin_amdgcn_s_waitcnt(0xC07F); __builtin_amdgcn_s_barrier(); } while (0)

__device__ __forceinline__ float block_sum(float v, float* sm) {
  int tid = threadIdx.x;
  sm[tid] = v;
  __syncthreads();
#pragma unroll
  for (int off = 128; off > 0; off >>= 1) {
    if (tid < off) sm[tid] += sm[tid + off];
    __syncthreads();
  }
  float r = sm[0];
  __syncthreads();
  return r;
}

__device__ __forceinline__ float block_min(float v, float* sm) {
  int tid = threadIdx.x;
  sm[tid] = v;
  __syncthreads();
#pragma unroll
  for (int off = 128; off > 0; off >>= 1) {
    if (tid < off) sm[tid] = fminf(sm[tid], sm[tid + off]);
    __syncthreads();
  }
  float r = sm[0];
  __syncthreads();
  return r;
}

__device__ __forceinline__ float wave_sum(float v) {
  v += __shfl_xor(v, 32); v += __shfl_xor(v, 16); v += __shfl_xor(v, 8);
  v += __shfl_xor(v, 4);  v += __shfl_xor(v, 2);  v += __shfl_xor(v, 1);
  return v;
}

__device__ __forceinline__ float wave_min(float v) {
  v = fminf(v, __shfl_xor(v, 32)); v = fminf(v, __shfl_xor(v, 16));
  v = fminf(v, __shfl_xor(v, 8));  v = fminf(v, __shfl_xor(v, 4));
  v = fminf(v, __shfl_xor(v, 2));  v = fminf(v, __shfl_xor(v, 1));
  return v;
}

// 7-tap sliding W-sum over 10 inputs -> 4 outputs (one float4 store, dense layout).
#define SLIDE7(V, M) do { \
  float s0 = ((V[0]+V[1])+(V[2]+V[3])) + ((V[4]+V[5])+V[6]); \
  float s1 = s0 - V[0] + V[7]; \
  float s2 = s1 - V[1] + V[8]; \
  float s3 = s2 - V[2] + V[9]; \
  *(float4*)&R[M][rA][c4] = make_float4(s0, s1, s2, s3); \
} while (0)

// (256,3): do NOT tighten to (256,4) — that caps unified VGPR/AGPR at 128 and
// forces the 70-float Z-history ring into scratch (round-2: 31 MB HBM writeback).
// VGPR tier 65..128 -> 16 waves/CU = 4 blocks; LDS 28.7KB -> 5 blocks; min = 4 either way.
__global__ __launch_bounds__(256, 3) void ncc_fused(const float* __restrict__ X,
                                                    const float* __restrict__ Y,
                                                    float* __restrict__ part) {
  __shared__ __align__(16) float R[5][14][64];   // 17.9 KB W-filtered moment rows
  __shared__ __align__(16) float Mh[5][HOT][64]; // 10.2 KB W+H-filtered moments
  __shared__ float red[4][5];

  const int tid = threadIdx.x;
  const int tx = tid & 63, ty = tid >> 6;
  const int wo0 = blockIdx.x * 64;
  const int ho0 = blockIdx.y * HOT;
  const int n   = blockIdx.z / ZCH;
  const int ck  = blockIdx.z % ZCH;
  const int z0  = ck * ZOC;

  const int wo = wo0 + tx;
  const bool act0 = (wo < WO) && (ho0 + ty < HO);
  const bool act1 = (wo < WO) && (ho0 + ty + 4 < HO);

  const size_t slice = (size_t)HH * WW;
  const float* Xn = X + (size_t)n * DD * slice;
  const float* Yn = Y + (size_t)n * DD * slice;
  const float inv_nw = 1.0f / 343.0f;
  const float LO = -1.0f - 1e-5f, HI = 1.0f + 1e-5f;

  // Phase-A item: 224 items; item p -> row rA=p>>4 (0..13), 4 outputs at cols c4..c4+3.
  const int pA  = tid;
  const bool hasA = (pA < 224);
  const int rA  = pA >> 4;
  const int c4  = (pA & 15) << 2;
  const int hA  = ho0 + rA;
  const int baseW = wo0 + c4;                  // multiple of 4
  const bool okA  = hasA && (hA < HH) && (baseW < WO);
  const bool tail = okA && (baseW + 10 > WW);  // only baseW==152: read 8, zero 2
  const float* XrowA = Xn + (size_t)hA * WW + baseW;
  const float* YrowA = Yn + (size_t)hA * WW + baseW;

  float4 lx0={0,0,0,0}, lx1={0,0,0,0};
  float4 ly0={0,0,0,0}, ly1={0,0,0,0};
  float2 lx2={0,0}, ly2={0,0};

  auto loadA = [&](int s_in) {
    if (okA) {
      const float* xp = XrowA + (size_t)(z0 + s_in) * slice;
      const float* yp = YrowA + (size_t)(z0 + s_in) * slice;
      lx0 = *(const float4*)xp;       lx1 = *(const float4*)(xp + 4);
      ly0 = *(const float4*)yp;       ly1 = *(const float4*)(yp + 4);
      if (!tail) { lx2 = *(const float2*)(xp + 8); ly2 = *(const float2*)(yp + 8); }
      else       { lx2 = make_float2(0.f, 0.f);    ly2 = make_float2(0.f, 0.f); }
    }
  };

  auto storeA = [&]() {
    if (okA) {
      const float x[10] = {lx0.x,lx0.y,lx0.z,lx0.w, lx1.x,lx1.y,lx1.z,lx1.w, lx2.x,lx2.y};
      const float y[10] = {ly0.x,ly0.y,ly0.z,ly0.w, ly1.x,ly1.y,ly1.z,ly1.w, ly2.x,ly2.y};
      SLIDE7(x, 0);
      SLIDE7(y, 1);
      {
        float t[10];
#pragma unroll
        for (int i = 0; i < 10; ++i) t[i] = x[i] * x[i];
        SLIDE7(t, 2);
      }
      {
        float t[10];
#pragma unroll
        for (int i = 0; i < 10; ++i) t[i] = y[i] * y[i];
        SLIDE7(t, 3);
      }
      {
        float t[10];
#pragma unroll
        for (int i = 0; i < 10; ++i) t[i] = x[i] * y[i];
        SLIDE7(t, 4);
      }
    }
  };

  // Phase H: 7-tap sliding H-sums, 14 rows -> 8 outputs per (ch, w). 320 items.
  auto phaseHitem = [&](int ch, int w) {
    const float* rp = &R[ch][0][w];
    float r0=rp[0],   r1=rp[64],  r2=rp[128], r3=rp[192], r4=rp[256],
          r5=rp[320], r6=rp[384], r7=rp[448], r8=rp[512], r9=rp[576],
          r10=rp[640], r11=rp[704], r12=rp[768], r13=rp[832];
    float m0 = ((r0+r1)+(r2+r3)) + ((r4+r5)+r6);
    float m1 = m0 - r0 + r7;
    float m2 = m1 - r1 + r8;
    float m3 = m2 - r2 + r9;
    float m4 = m3 - r3 + r10;
    float m5 = m4 - r4 + r11;
    float m6 = m5 - r5 + r12;
    float m7 = m6 - r6 + r13;
    Mh[ch][0][w]=m0; Mh[ch][1][w]=m1; Mh[ch][2][w]=m2; Mh[ch][3][w]=m3;
    Mh[ch][4][w]=m4; Mh[ch][5][w]=m5; Mh[ch][6][w]=m6; Mh[ch][7][w]=m7;
  };
  auto phaseH = [&]() {
    phaseHitem(ty, tx);
    if (ty == 3) phaseHitem(4, tx);   // wave 3's phase-A is half-masked -> give it ch4
  };

  // Sliding-window Z accumulation: zs += m_new - hist[u]; hist[u] = m_new.
  // Ring index u is static (loop unrolled by 7) -> stays in registers/AGPRs.
  float zs0[2]={0,0}, zs1[2]={0,0}, zs2[2]={0,0}, zs3[2]={0,0}, zs4[2]={0,0};
  float h0[2][7], h1[2][7], h2[2][7], h3[2][7], h4[2][7];
#pragma unroll
  for (int j = 0; j < 7; ++j) {
    h0[0][j]=0.f; h1[0][j]=0.f; h2[0][j]=0.f; h3[0][j]=0.f; h4[0][j]=0.f;
    h0[1][j]=0.f; h1[1][j]=0.f; h2[1][j]=0.f; h3[1][j]=0.f; h4[1][j]=0.f;
  }
  float p_snv = 0.f, p_sn = 0.f, p_sv = 0.f, p_cnt = 0.f, p_vmin = 3.4e38f;

  loadA(0);
  storeA();
  __syncthreads();

#pragma unroll 1
  for (int sb = 0; sb < NSL; sb += 7) {     // NSL = 28 = 4*7 for EVERY block
#pragma unroll
    for (int u = 0; u < 7; ++u) {
      const int s = sb + u;
      if (s + 1 < NSL) loadA(s + 1);        // global -> regs (stays in flight)
      phaseH();                             // R -> Mh
      LDS_SYNC();
      {                                     // Phase O: Mh -> sliding-Z + epilogue
#pragma unroll
        for (int rb = 0; rb < 2; ++rb) {
          const int row = ty + (rb << 2);
          float m0 = Mh[0][row][tx], m1 = Mh[1][row][tx], m2 = Mh[2][row][tx],
                m3 = Mh[3][row][tx], m4 = Mh[4][row][tx];
          zs0[rb] += m0 - h0[rb][u]; h0[rb][u] = m0;
          zs1[rb] += m1 - h1[rb][u]; h1[rb][u] = m1;
          zs2[rb] += m2 - h2[rb][u]; h2[rb][u] = m2;
          zs3[rb] += m3 - h3[rb][u]; h3[rb][u] = m3;
          zs4[rb] += m4 - h4[rb][u]; h4[rb][u] = m4;
          if (s >= 6 && (rb ? act1 : act0)) {
            float num = zs4[rb] - zs0[rb] * zs1[rb] * inv_nw;
            float d0  = zs2[rb] - zs0[rb] * zs0[rb] * inv_nw;
            float d1  = zs3[rb] - zs1[rb] * zs1[rb] * inv_nw;
            float den = d0 * d1;
            if (den > 1e-5f) {
              float ncc = num * __frsqrt_rn(den);
              if (ncc >= LO && ncc <= HI) {
                float v = 0.5f * (d0 + d1);
                p_snv += ncc * v; p_sn += ncc; p_sv += v; p_cnt += 1.f;
                p_vmin = fminf(p_vmin, v);
              }
            }
          }
        }
      }
      if (s + 1 < NSL) storeA();            // vmcnt wait lands HERE
      LDS_SYNC();
    }
  }

  // Wave-level reduction (6 shfl each), then 4 partials through LDS.
  float r0 = wave_sum(p_snv);
  float r1 = wave_sum(p_sn);
  float r2 = wave_sum(p_sv);
  float r3 = wave_sum(p_cnt);
  float r4 = wave_min(p_vmin);
  if (tx == 0) {
    red[ty][0]=r0; red[ty][1]=r1; red[ty][2]=r2; red[ty][3]=r3; red[ty][4]=r4;
  }
  __syncthreads();
  if (tid == 0) {
    float s0 = (red[0][0]+red[1][0]) + (red[2][0]+red[3][0]);
    float s1 = (red[0][1]+red[1][1]) + (red[2][1]+red[3][1]);
    float s2 = (red[0][2]+red[1][2]) + (red[2][2]+red[3][2]);
    float s3 = (red[0][3]+red[1][3]) + (red[2][3]+red[3][3]);
    float s4 = fminf(fminf(red[0][4],red[1][4]), fminf(red[2][4],red[3][4]));
    const int bid = blockIdx.x + NWO * (blockIdx.y + NHO * blockIdx.z);
    float* pp = part + (size_t)bid * 8;
    pp[0] = s0; pp[1] = s1; pp[2] = s2; pp[3] = s3; pp[4] = s4;
  }
}

// Reduce NB per-block partials; loss = 1 - (S_nv - vmin*S_n)/(S_v - vmin*cnt)
// (the min-max weight scale HIGH/(vmax-vmin+1e-12) cancels in w/sum(w)).
__global__ __launch_bounds__(256) void fin(const float* __restrict__ part,
                                           float* __restrict__ out) {
  __shared__ float sm[256];
  const int tid = threadIdx.x;
  float s0 = 0.f, s1 = 0.f, s2 = 0.f, s3 = 0.f, vm = 3.4e38f;
  for (int b = tid; b < NB; b += 256) {
    const float* pp = part + (size_t)b * 8;
    s0 += pp[0]; s1 += pp[1]; s2 += pp[2]; s3 += pp[3];
    vm = fminf(vm, pp[4]);
  }
  s0 = block_sum(s0, sm);
  s1 = block_sum(s1, sm);
  s2 = block_sum(s2, sm);
  s3 = block_sum(s3, sm);
  vm = block_min(vm, sm);
  if (tid == 0) {
    out[0] = 1.0f - (s0 - vm * s1) / (s2 - vm * s3);
  }
}

extern "C" void kernel_launch(void* const* d_in, const int* in_sizes, int n_in,
                              void* d_out, int out_size, void* d_ws, size_t ws_size,
                              hipStream_t stream) {
  const float* X = (const float*)d_in[0];  // y_pred
  const float* Y = (const float*)d_in[1];  // y_true
  // d_in[2]: ones kernel, constant, unused.

  float* part = (float*)d_ws;  // NB * 8 floats = 31.5 KB

  dim3 g(NWO, NHO, NN * ZCH);
  ncc_fused<<<g, 256, 0, stream>>>(X, Y, part);
  fin<<<1, 256, 0, stream>>>(part, (float*)d_out);
}